// Round 1
// baseline (3569.478 us; speedup 1.0000x reference)
//
#include <hip/hip_runtime.h>
#include <cstdint>
#include <cstddef>

#define DIM 64

// ---- output element offsets (float32 elements, reference return order) ----
static constexpr size_t OFF_FH = 0;                  // fused_H   [32768][3584]
static constexpr size_t OFF_H0 = 117440512;          // H0        [32768][2048]
static constexpr size_t OFF_H1 = 184549376;          // H1        [16384][1024]
static constexpr size_t OFF_H2 = 201326592;          // H2        [8192][512]
static constexpr size_t OFF_B0 = 205520896;          // bins0
static constexpr size_t OFF_B1 = 272629760;          // bins1
static constexpr size_t OFF_B2 = 289406976;          // bins2 (also used as scratch for topk0/topk1)
static constexpr size_t OFF_FB = 293601280;          // fused_bin [32768][3584]
static constexpr size_t OFF_R0 = 411041792;          // retain0 [2048]
static constexpr size_t OFF_R1 = 411043840;          // retain1 [1024]
static constexpr size_t OFF_R2 = 411044864;          // retain2 [512]
static constexpr size_t OFF_RF = 411045376;          // fused_retain [3584]

__device__ __forceinline__ float dot4(float4 a, float4 b, float acc) {
  acc = fmaf(a.x, b.x, acc);
  acc = fmaf(a.y, b.y, acc);
  acc = fmaf(a.z, b.z, acc);
  acc = fmaf(a.w, b.w, acc);
  return acc;
}

// Zero the retain outputs (they are only sparsely set later) and seed ws atomics.
__global__ void k_init(float* __restrict__ out, unsigned int* __restrict__ wsMM,
                       unsigned long long* __restrict__ wsBlend) {
  const int t = threadIdx.x;
  for (int i = t; i < 7168; i += 256) out[OFF_R0 + i] = 0.0f;
  if (t < 3) {
    wsMM[2 * t + 0] = 0x7F7FFFFFu;  // FLT_MAX bits (init min)
    wsMM[2 * t + 1] = 0u;           // init max (all init values > 0)
    wsBlend[t] = 0ull;              // blend max (positive doubles)
  }
}

// k1: per 16-row block: f32 GEMM (k-sliced, shuffle-reduced), online softmax
// stats, per-thread packed top-8 -> row top-16, f64 head recompute, topk store,
// blend-max atomic; plus streaming min/max of adj_init.
__global__ __launch_bounds__(256) void k1(
    const float* __restrict__ node, const float* __restrict__ edge,
    const float* __restrict__ init, int E,
    int* __restrict__ tIdx, double* __restrict__ tCur,
    unsigned int* __restrict__ wsMM, unsigned long long* __restrict__ wsBlend) {
  __shared__ float xt[16][272];   // x-tile: 16 rows x 256 cols (stride 272 -> 2-way banks only)
  __shared__ float sMin[4], sMax[4];
  __shared__ double sBlend[16];

  const int t = threadIdx.x;
  const int lane = t & 63;
  const int wave = t >> 6;
  const int row0 = blockIdx.x * 16;
  const int kt = lane & 3;        // k-slice id (16 k's each)
  const int csub = lane >> 2;     // 0..15 col-in-batch

  // node block in registers: 16 rows x this thread's 16-k slice
  float4 nd[16][4];
#pragma unroll
  for (int r = 0; r < 16; ++r) {
    const float4* np_ = (const float4*)(node + (size_t)(row0 + r) * DIM + kt * 16);
#pragma unroll
    for (int j = 0; j < 4; ++j) nd[r][j] = np_[j];
  }

  // online softmax state + packed top-8 (val<<32 | (~col) : index tie-break = lower col wins)
  float m = 0.0f;
  double s = 0.0;
  unsigned long long top[8];
#pragma unroll
  for (int q = 0; q < 8; ++q) top[q] = (unsigned long long)q;  // unique sentinels < any real pack
  unsigned long long tmin = 0ull;

  const int sr = t >> 4;  // scan row (0..15)
  const int sl = t & 15;  // scan lane within row (0..15)

  const int nTiles = E >> 8;
  for (int tile = 0; tile < nTiles; ++tile) {
    const int cb0 = tile << 8;
    // ---- GEMM phase: wave handles 4 batches of 16 cols ----
#pragma unroll 1
    for (int b = 0; b < 4; ++b) {
      const int cloc = wave * 64 + b * 16 + csub;
      const int c = cb0 + cloc;
      const float4* ep = (const float4*)(edge + (size_t)c * DIM + kt * 16);
      float4 e0 = ep[0], e1 = ep[1], e2 = ep[2], e3 = ep[3];
#pragma unroll
      for (int r = 0; r < 16; ++r) {
        float p = 0.0f;
        p = dot4(nd[r][0], e0, p);
        p = dot4(nd[r][1], e1, p);
        p = dot4(nd[r][2], e2, p);
        p = dot4(nd[r][3], e3, p);
        p += __shfl_xor(p, 1);
        p += __shfl_xor(p, 2);
        if (kt == 0) xt[r][cloc] = fmaxf(3.0f * p, 0.0f);
      }
    }
    __syncthreads();
    // ---- scan phase: 16 threads per row, 16 cols each ----
#pragma unroll 1
    for (int j = 0; j < 16; ++j) {
      const int cc = sl + (j << 4);
      const float v = xt[sr][cc];
      const float nm = fmaxf(m, v);
      s = s * (double)expf(m - nm) + (double)expf(v - nm);
      m = nm;
      const unsigned int gc = (unsigned int)(cb0 + cc);
      const unsigned long long pk =
          ((unsigned long long)__float_as_uint(v) << 32) |
          (unsigned long long)(0xFFFFFFFFu - gc);
      if (pk > tmin) {
#pragma unroll
        for (int q = 0; q < 8; ++q) top[q] = (top[q] == tmin) ? pk : top[q];
        unsigned long long t2 = top[0];
#pragma unroll
        for (int q = 1; q < 8; ++q) t2 = (top[q] < t2) ? top[q] : t2;
        tmin = t2;
      }
    }
    __syncthreads();
  }

  // ---- combine per-thread softmax stats across the row's 16 threads ----
  float m32 = m;
#pragma unroll
  for (int d = 1; d < 16; d <<= 1) m32 = fmaxf(m32, __shfl_xor(m32, d));
  double sFull = s * exp((double)(m - m32));
#pragma unroll
  for (int d = 1; d < 16; d <<= 1) sFull += __shfl_xor(sFull, d);

  // ---- merge 16x top-8 -> global top-16; thread sl ends holding rank-sl ----
  unsigned long long mywin = 0ull;
#pragma unroll 1
  for (int round = 0; round < 16; ++round) {
    unsigned long long lm = top[0];
#pragma unroll
    for (int q = 1; q < 8; ++q) lm = (top[q] > lm) ? top[q] : lm;
#pragma unroll
    for (int d = 1; d < 16; d <<= 1) {
      unsigned long long o = __shfl_xor(lm, d);
      lm = (o > lm) ? o : lm;
    }
#pragma unroll
    for (int q = 0; q < 8; ++q) top[q] = (top[q] == lm) ? 0ull : top[q];
    if (round == sl) mywin = lm;
  }

  // ---- f64 head recompute for this thread's candidate ----
  const float x32 = __uint_as_float((unsigned int)(mywin >> 32));
  const unsigned int gc = 0xFFFFFFFFu - (unsigned int)(mywin & 0xFFFFFFFFull);
  const int grow = row0 + sr;
  const float4* e4 = (const float4*)(edge + (size_t)gc * DIM);
  const float4* n4 = (const float4*)(node + (size_t)grow * DIM);
  double acc = 0.0;
#pragma unroll
  for (int j = 0; j < 16; ++j) {
    float4 a = n4[j], bb = e4[j];
    acc += (double)a.x * (double)bb.x;
    acc += (double)a.y * (double)bb.y;
    acc += (double)a.z * (double)bb.z;
    acc += (double)a.w * (double)bb.w;
  }
  const double x64 = fmax(3.0 * acc, 0.0);
  const double eh = exp(x64 - (double)m32);
  const double h32 = (double)expf(x32 - m32);
  double sumEh = eh, sumH32 = h32;
#pragma unroll
  for (int d = 1; d < 16; d <<= 1) {
    sumEh += __shfl_xor(sumEh, d);
    sumH32 += __shfl_xor(sumH32, d);
  }
  const double sFix = fmax(sFull - sumH32, 0.0) + sumEh;  // tail (f32-grade, tiny weight) + f64 head
  const double cur = eh / sFix;
  tIdx[(size_t)grow * 16 + sl] = (int)gc;
  tCur[(size_t)grow * 16 + sl] = cur;

  double blend = 0.5 * ((double)init[(size_t)grow * E + (int)gc] + cur);
#pragma unroll
  for (int d = 1; d < 16; d <<= 1) {
    double o = __shfl_xor(blend, d);
    blend = fmax(blend, o);
  }
  if (sl == 0) sBlend[sr] = blend;

  // ---- streaming min/max of adj_init for this block's 16 rows ----
  float imn = __uint_as_float(0x7F7FFFFFu), imx = 0.0f;
  const float4* ib = (const float4*)(init + (size_t)row0 * E);
  const int tot = (16 * E) >> 2;
  for (int i = t; i < tot; i += 256) {
    float4 v = ib[i];
    imn = fminf(imn, fminf(fminf(v.x, v.y), fminf(v.z, v.w)));
    imx = fmaxf(imx, fmaxf(fmaxf(v.x, v.y), fmaxf(v.z, v.w)));
  }
#pragma unroll
  for (int d = 1; d < 64; d <<= 1) {
    imn = fminf(imn, __shfl_xor(imn, d));
    imx = fmaxf(imx, __shfl_xor(imx, d));
  }
  if (lane == 0) { sMin[wave] = imn; sMax[wave] = imx; }
  __syncthreads();
  if (t == 0) {
    float a = fminf(fminf(sMin[0], sMin[1]), fminf(sMin[2], sMin[3]));
    float b = fmaxf(fmaxf(sMax[0], sMax[1]), fmaxf(sMax[2], sMax[3]));
    atomicMin(wsMM + 0, __float_as_uint(a));
    atomicMax(wsMM + 1, __float_as_uint(b));
    double bl = sBlend[0];
#pragma unroll
    for (int i = 1; i < 16; ++i) bl = fmax(bl, sBlend[i]);
    atomicMax(wsBlend, (unsigned long long)__double_as_longlong(bl));
  }
}

// k2: per-row normalize + binarize + fused copies; f32 base pass (values are
// far from 0.5 off the top-k), then 16-thread f64 fix-up of top-k entries.
__global__ __launch_bounds__(256) void k2(
    const float* __restrict__ init, int E, int factor, int foff,
    const int* __restrict__ tIdx, const double* __restrict__ tCur,
    const unsigned int* __restrict__ wsMM,
    const unsigned long long* __restrict__ wsBlend,
    float* __restrict__ outH, float* __restrict__ outB,
    float* __restrict__ outFH, float* __restrict__ outFB,
    float* __restrict__ outR, float* __restrict__ outFR) {
  const int r = blockIdx.x;
  const int t = threadIdx.x;
  const double mn = 0.5 * (double)__uint_as_float(wsMM[0]);
  const double mx = fmax(0.5 * (double)__uint_as_float(wsMM[1]),
                         __longlong_as_double((long long)wsBlend[0]));
  const double inv = 1.0 / (mx - mn);
  const float mnf = (float)mn, invf = (float)inv;

  const float4* ib = (const float4*)(init + (size_t)r * E);
  float4* hRow = (float4*)(outH + (size_t)r * E);
  float4* bRow = (float4*)(outB + (size_t)r * E);
  const int nf4 = E >> 2;
  for (int i = t; i < nf4; i += 256) {
    float4 v = ib[i];
    float4 h, bb;
    h.x = (0.5f * v.x - mnf) * invf;
    h.y = (0.5f * v.y - mnf) * invf;
    h.z = (0.5f * v.z - mnf) * invf;
    h.w = (0.5f * v.w - mnf) * invf;
    bb.x = (h.x > 0.5f) ? 1.0f : 0.0f;
    bb.y = (h.y > 0.5f) ? 1.0f : 0.0f;
    bb.z = (h.z > 0.5f) ? 1.0f : 0.0f;
    bb.w = (h.w > 0.5f) ? 1.0f : 0.0f;
    hRow[i] = h;
    bRow[i] = bb;
    for (int f = 0; f < factor; ++f) {
      float4* fh = (float4*)(outFH + ((size_t)r * factor + f) * 3584 + foff);
      float4* fb = (float4*)(outFB + ((size_t)r * factor + f) * 3584 + foff);
      fh[i] = h;
      fb[i] = bb;
    }
    if (bb.x + bb.y + bb.z + bb.w > 0.0f) {  // essentially never taken off top-k
      const int c0 = i << 2;
      if (bb.x > 0.0f) { outR[c0 + 0] = 1.0f; outFR[foff + c0 + 0] = 1.0f; }
      if (bb.y > 0.0f) { outR[c0 + 1] = 1.0f; outFR[foff + c0 + 1] = 1.0f; }
      if (bb.z > 0.0f) { outR[c0 + 2] = 1.0f; outFR[foff + c0 + 2] = 1.0f; }
      if (bb.w > 0.0f) { outR[c0 + 3] = 1.0f; outFR[foff + c0 + 3] = 1.0f; }
    }
  }
  __syncthreads();
  if (t < 16) {
    const int gc = tIdx[(size_t)r * 16 + t];
    const double cur = tCur[(size_t)r * 16 + t];
    const double adj = 0.5 * ((double)init[(size_t)r * E + gc] + cur);
    const double H = (adj - mn) * inv;
    const float hf = (float)H;
    const float bf = (H > 0.5) ? 1.0f : 0.0f;
    outH[(size_t)r * E + gc] = hf;
    outB[(size_t)r * E + gc] = bf;
    for (int f = 0; f < factor; ++f) {
      outFH[((size_t)r * factor + f) * 3584 + foff + gc] = hf;
      outFB[((size_t)r * factor + f) * 3584 + foff + gc] = bf;
    }
    if (bf > 0.0f) {
      outR[gc] = 1.0f;       // idempotent 1.0f stores: race-safe
      outFR[foff + gc] = 1.0f;
    }
  }
}

extern "C" void kernel_launch(void* const* d_in, const int* in_sizes, int n_in,
                              void* d_out, int out_size, void* d_ws, size_t ws_size,
                              hipStream_t stream) {
  (void)in_sizes; (void)n_in; (void)out_size; (void)ws_size;
  const float* node0 = (const float*)d_in[0];
  const float* node1 = (const float*)d_in[1];
  const float* node2 = (const float*)d_in[2];
  const float* edge0 = (const float*)d_in[3];
  const float* edge1 = (const float*)d_in[4];
  const float* edge2 = (const float*)d_in[5];
  const float* init0 = (const float*)d_in[6];
  const float* init1 = (const float*)d_in[7];
  const float* init2 = (const float*)d_in[8];
  float* out = (float*)d_out;

  // ws layout: [0..23] u32 min/max per level; [32..55] u64 blend max; topk2 after.
  unsigned char* ws = (unsigned char*)d_ws;
  unsigned int* wsMM = (unsigned int*)ws;
  unsigned long long* wsBlend = (unsigned long long*)(ws + 32);
  int* tIdx2 = (int*)(ws + 64);
  double* tCur2 = (double*)(ws + 64 + 524288);

  // topk0/topk1 scratch inside bins2 output region (consumed before k2 level2 rewrites it)
  float* b2s = out + OFF_B2;
  int* tIdx0 = (int*)b2s;                     // 524288 floats
  double* tCur0 = (double*)(b2s + 524288);    // 1048576 floats
  int* tIdx1 = (int*)(b2s + 1572864);         // 262144 floats
  double* tCur1 = (double*)(b2s + 1835008);   // 524288 floats

  k_init<<<1, 256, 0, stream>>>(out, wsMM, wsBlend);
  k1<<<2048, 256, 0, stream>>>(node0, edge0, init0, 2048, tIdx0, tCur0, wsMM + 0, wsBlend + 0);
  k1<<<1024, 256, 0, stream>>>(node1, edge1, init1, 1024, tIdx1, tCur1, wsMM + 2, wsBlend + 1);
  k1<<<512, 256, 0, stream>>>(node2, edge2, init2, 512, tIdx2, tCur2, wsMM + 4, wsBlend + 2);
  k2<<<32768, 256, 0, stream>>>(init0, 2048, 1, 0, tIdx0, tCur0, wsMM + 0, wsBlend + 0,
                                out + OFF_H0, out + OFF_B0, out + OFF_FH, out + OFF_FB,
                                out + OFF_R0, out + OFF_RF);
  k2<<<16384, 256, 0, stream>>>(init1, 1024, 2, 2048, tIdx1, tCur1, wsMM + 2, wsBlend + 1,
                                out + OFF_H1, out + OFF_B1, out + OFF_FH, out + OFF_FB,
                                out + OFF_R1, out + OFF_RF);
  k2<<<8192, 256, 0, stream>>>(init2, 512, 4, 3072, tIdx2, tCur2, wsMM + 4, wsBlend + 2,
                                out + OFF_H2, out + OFF_B2, out + OFF_FH, out + OFF_FB,
                                out + OFF_R2, out + OFF_RF);
}

// Round 2
// 2962.419 us; speedup vs baseline: 1.2049x; 1.2049x over previous
//
#include <hip/hip_runtime.h>
#include <cstdint>
#include <cstddef>

#define DIM 64

// ---- output element offsets (float32 elements, reference return order) ----
static constexpr size_t OFF_FH = 0;                  // fused_H   [32768][3584]
static constexpr size_t OFF_H0 = 117440512;          // H0        [32768][2048]
static constexpr size_t OFF_H1 = 184549376;          // H1        [16384][1024]
static constexpr size_t OFF_H2 = 201326592;          // H2        [8192][512]
static constexpr size_t OFF_B0 = 205520896;          // bins0
static constexpr size_t OFF_B1 = 272629760;          // bins1
static constexpr size_t OFF_B2 = 289406976;          // bins2 (also used as scratch for topk0/topk1)
static constexpr size_t OFF_FB = 293601280;          // fused_bin [32768][3584]
static constexpr size_t OFF_R0 = 411041792;          // retain0 [2048]
static constexpr size_t OFF_R1 = 411043840;          // retain1 [1024]
static constexpr size_t OFF_R2 = 411044864;          // retain2 [512]
static constexpr size_t OFF_RF = 411045376;          // fused_retain [3584]

// f32-grade exp(x) as a double, x >= 0, chain-free (no running max needed):
// split x*log2e into int + frac, v_exp_f32 on frac, exponent via f64 bit-build.
__device__ __forceinline__ double exp2split(float x) {
  const float f = x * 1.44269504f;
  const int i = (int)f;              // trunc; f >= 0
  const float r = f - (float)i;
  const float e = exp2f(r);          // v_exp_f32, r in [0,1)
  const unsigned long long sc = (unsigned long long)(1023 + i) << 52;
  return (double)e * __longlong_as_double((long long)sc);
}

__device__ __forceinline__ void scan1(float x, int col, unsigned long long* top,
                                      unsigned long long& tmin, double& s) {
  const unsigned long long pk =
      ((unsigned long long)__float_as_uint(x) << 32) |
      (unsigned long long)(0xFFFFFFFFu - (unsigned int)col);
  if (pk > tmin) {  // replace current min of the 16-deep list
#pragma unroll
    for (int q = 0; q < 16; ++q) top[q] = (top[q] == tmin) ? pk : top[q];
    unsigned long long t2 = top[0];
#pragma unroll
    for (int q = 1; q < 16; ++q) t2 = (top[q] < t2) ? top[q] : t2;
    tmin = t2;
  }
  s += exp2split(x);
}

// Zero the retain outputs (sparsely set later) and seed ws atomics.
__global__ void k_init(float* __restrict__ out, unsigned int* __restrict__ wsMM,
                       unsigned long long* __restrict__ wsBlend) {
  const int t = threadIdx.x;
  for (int i = t; i < 7168; i += 256) out[OFF_R0 + i] = 0.0f;
  if (t < 3) {
    wsMM[2 * t + 0] = 0x7F7FFFFFu;  // FLT_MAX bits (init min)
    wsMM[2 * t + 1] = 0u;           // init max (all init values > 0)
    wsBlend[t] = 0ull;              // blend max (positive doubles)
  }
}

// k1 v2: 64x64 LDS-tiled GEMM (4x4 register tile, k-major buffers, no shuffles
// in the inner loop), chain-free exp2-split softmax sum, capacity-16 per-thread
// top-k (4 scan threads/row -> absolutely safe), f64 head fix, blend max,
// streaming init min/max.
__global__ __launch_bounds__(256) void k1(
    const float* __restrict__ node, const float* __restrict__ edge,
    const float* __restrict__ init, int E,
    int* __restrict__ tIdx, double* __restrict__ tCur,
    unsigned int* __restrict__ wsMM, unsigned long long* __restrict__ wsBlend) {
  __shared__ float nodeT[64][68];  // k-major: nodeT[k][r]
  __shared__ float eT[64][68];     // k-major: eT[k][c]
  __shared__ float xt[64][68];     // x-tile: xt[r][c]
  __shared__ float sMin[4], sMax[4];
  __shared__ double sBlendW[4];

  const int t = threadIdx.x;
  const int lane = t & 63;
  const int wave = t >> 6;
  const int row0 = blockIdx.x * 64;

  // stage nodeT (transposed): per wave, lane r covers one row, wave = k-quarter
  {
    const int r = lane;
    const float4* src = (const float4*)(node + (size_t)(row0 + r) * DIM + wave * 16);
#pragma unroll
    for (int q = 0; q < 4; ++q) {
      float4 v = src[q];
      const int k = wave * 16 + q * 4;
      nodeT[k + 0][r] = v.x; nodeT[k + 1][r] = v.y;
      nodeT[k + 2][r] = v.z; nodeT[k + 3][r] = v.w;
    }
  }

  const int ry4 = (t >> 4) << 2;  // GEMM rows 4*(t>>4)
  const int cx4 = (t & 15) << 2;  // GEMM cols 4*(t&15)
  const int srow = t >> 2;        // scan row (0..63)
  const int sl = t & 3;           // scan lane within row (0..3)

  unsigned long long top[16];
#pragma unroll
  for (int q = 0; q < 16; ++q) top[q] = (unsigned long long)q;  // unique sentinels < any real pack
  unsigned long long tmin = 0ull;
  double s0 = 0.0, s1 = 0.0;

  for (int c0 = 0; c0 < E; c0 += 64) {
    __syncthreads();  // previous tile's eT readers + xt scanners done (and nodeT staged, iter 0)
    {                 // stage eT (transposed), same mapping as nodeT
      const int c = lane;
      const float4* src = (const float4*)(edge + (size_t)(c0 + c) * DIM + wave * 16);
#pragma unroll
      for (int q = 0; q < 4; ++q) {
        float4 v = src[q];
        const int k = wave * 16 + q * 4;
        eT[k + 0][c] = v.x; eT[k + 1][c] = v.y;
        eT[k + 2][c] = v.z; eT[k + 3][c] = v.w;
      }
    }
    __syncthreads();

    // ---- 64x64 GEMM, 4x4 per thread ----
    float acc[4][4];
#pragma unroll
    for (int i = 0; i < 4; ++i)
#pragma unroll
      for (int j = 0; j < 4; ++j) acc[i][j] = 0.0f;

#pragma unroll 4
    for (int k = 0; k < 64; ++k) {
      const float4 a = *(const float4*)&nodeT[k][ry4];
      const float4 b = *(const float4*)&eT[k][cx4];
      acc[0][0] = fmaf(a.x, b.x, acc[0][0]); acc[0][1] = fmaf(a.x, b.y, acc[0][1]);
      acc[0][2] = fmaf(a.x, b.z, acc[0][2]); acc[0][3] = fmaf(a.x, b.w, acc[0][3]);
      acc[1][0] = fmaf(a.y, b.x, acc[1][0]); acc[1][1] = fmaf(a.y, b.y, acc[1][1]);
      acc[1][2] = fmaf(a.y, b.z, acc[1][2]); acc[1][3] = fmaf(a.y, b.w, acc[1][3]);
      acc[2][0] = fmaf(a.z, b.x, acc[2][0]); acc[2][1] = fmaf(a.z, b.y, acc[2][1]);
      acc[2][2] = fmaf(a.z, b.z, acc[2][2]); acc[2][3] = fmaf(a.z, b.w, acc[2][3]);
      acc[3][0] = fmaf(a.w, b.x, acc[3][0]); acc[3][1] = fmaf(a.w, b.y, acc[3][1]);
      acc[3][2] = fmaf(a.w, b.z, acc[3][2]); acc[3][3] = fmaf(a.w, b.w, acc[3][3]);
    }

    // epilogue: x = relu(3*a) -> xt
#pragma unroll
    for (int i = 0; i < 4; ++i) {
      float4 h;
      h.x = fmaxf(3.0f * acc[i][0], 0.0f);
      h.y = fmaxf(3.0f * acc[i][1], 0.0f);
      h.z = fmaxf(3.0f * acc[i][2], 0.0f);
      h.w = fmaxf(3.0f * acc[i][3], 0.0f);
      *(float4*)&xt[ry4 + i][cx4] = h;
    }
    __syncthreads();

    // ---- scan: 4 threads per row, 16 cols each ----
#pragma unroll
    for (int j = 0; j < 4; ++j) {
      const float4 v = *(const float4*)&xt[srow][sl * 16 + 4 * j];
      const int cb = c0 + sl * 16 + 4 * j;
      scan1(v.x, cb + 0, top, tmin, s0);
      scan1(v.y, cb + 1, top, tmin, s1);
      scan1(v.z, cb + 2, top, tmin, s0);
      scan1(v.w, cb + 3, top, tmin, s1);
    }
  }

  // ---- merge 4x top-16 -> row top-16; round r winner -> thread (r&3), slot r>>2 ----
  unsigned long long win[4];
#pragma unroll 1
  for (int round = 0; round < 16; ++round) {
    unsigned long long lm = top[0];
#pragma unroll
    for (int q = 1; q < 16; ++q) lm = (top[q] > lm) ? top[q] : lm;
    { unsigned long long o = __shfl_xor(lm, 1); lm = (o > lm) ? o : lm; }
    { unsigned long long o = __shfl_xor(lm, 2); lm = (o > lm) ? o : lm; }
#pragma unroll
    for (int q = 0; q < 16; ++q) top[q] = (top[q] == lm) ? 0ull : top[q];
    if ((round & 3) == sl) win[round >> 2] = lm;
  }

  // ---- full row sum (f32-grade tail, doubles) ----
  double sAll = s0 + s1;
  sAll += __shfl_xor(sAll, 1);
  sAll += __shfl_xor(sAll, 2);

  // ---- f64 head recompute (4 winners per thread) ----
  const int grow = row0 + srow;
  const float4* n4 = (const float4*)(node + (size_t)grow * DIM);
  double eh[4];
  int gcv[4];
  double h32sum = 0.0, ehsum = 0.0;
#pragma unroll 1
  for (int w = 0; w < 4; ++w) {
    const float x32 = __uint_as_float((unsigned int)(win[w] >> 32));
    const unsigned int gc = 0xFFFFFFFFu - (unsigned int)(win[w] & 0xFFFFFFFFull);
    const float4* e4 = (const float4*)(edge + (size_t)gc * DIM);
    double acc = 0.0;
#pragma unroll
    for (int j = 0; j < 16; ++j) {
      const float4 a = n4[j], b = e4[j];
      acc += (double)a.x * (double)b.x + (double)a.y * (double)b.y +
             (double)a.z * (double)b.z + (double)a.w * (double)b.w;
    }
    const double x64 = fmax(3.0 * acc, 0.0);
    eh[w] = exp(x64);
    ehsum += eh[w];
    h32sum += exp2split(x32);
    gcv[w] = (int)gc;
  }
  h32sum += __shfl_xor(h32sum, 1); h32sum += __shfl_xor(h32sum, 2);
  ehsum  += __shfl_xor(ehsum, 1);  ehsum  += __shfl_xor(ehsum, 2);
  const double sFix = fmax(sAll - h32sum, 0.0) + ehsum;  // swap f32-grade head for f64 head

  double blend = 0.0;
#pragma unroll 1
  for (int w = 0; w < 4; ++w) {
    const double cur = eh[w] / sFix;
    tIdx[(size_t)grow * 16 + 4 * w + sl] = gcv[w];
    tCur[(size_t)grow * 16 + 4 * w + sl] = cur;
    const double bl = 0.5 * ((double)init[(size_t)grow * E + gcv[w]] + cur);
    blend = fmax(blend, bl);
  }
#pragma unroll
  for (int d = 1; d < 64; d <<= 1) {
    const double o = __shfl_xor(blend, d);
    blend = fmax(blend, o);
  }
  if (lane == 0) sBlendW[wave] = blend;

  // ---- streaming min/max of adj_init for this block's 64 rows ----
  float imn = __uint_as_float(0x7F7FFFFFu), imx = 0.0f;
  const float4* ib = (const float4*)(init + (size_t)row0 * E);
  const int tot = (64 * E) >> 2;
  for (int i = t; i < tot; i += 256) {
    const float4 v = ib[i];
    imn = fminf(imn, fminf(fminf(v.x, v.y), fminf(v.z, v.w)));
    imx = fmaxf(imx, fmaxf(fmaxf(v.x, v.y), fmaxf(v.z, v.w)));
  }
#pragma unroll
  for (int d = 1; d < 64; d <<= 1) {
    imn = fminf(imn, __shfl_xor(imn, d));
    imx = fmaxf(imx, __shfl_xor(imx, d));
  }
  if (lane == 0) { sMin[wave] = imn; sMax[wave] = imx; }
  __syncthreads();
  if (t == 0) {
    const float a = fminf(fminf(sMin[0], sMin[1]), fminf(sMin[2], sMin[3]));
    const float b = fmaxf(fmaxf(sMax[0], sMax[1]), fmaxf(sMax[2], sMax[3]));
    atomicMin(wsMM + 0, __float_as_uint(a));
    atomicMax(wsMM + 1, __float_as_uint(b));
    double bl = sBlendW[0];
#pragma unroll
    for (int i = 1; i < 4; ++i) bl = fmax(bl, sBlendW[i]);
    atomicMax(wsBlend, (unsigned long long)__double_as_longlong(bl));
  }
}

// k2: per-row normalize + binarize + fused copies; f32 base pass (values are
// far from 0.5 off the top-k), then 16-thread f64 fix-up of top-k entries.
__global__ __launch_bounds__(256) void k2(
    const float* __restrict__ init, int E, int factor, int foff,
    const int* __restrict__ tIdx, const double* __restrict__ tCur,
    const unsigned int* __restrict__ wsMM,
    const unsigned long long* __restrict__ wsBlend,
    float* __restrict__ outH, float* __restrict__ outB,
    float* __restrict__ outFH, float* __restrict__ outFB,
    float* __restrict__ outR, float* __restrict__ outFR) {
  const int r = blockIdx.x;
  const int t = threadIdx.x;
  const double mn = 0.5 * (double)__uint_as_float(wsMM[0]);
  const double mx = fmax(0.5 * (double)__uint_as_float(wsMM[1]),
                         __longlong_as_double((long long)wsBlend[0]));
  const double inv = 1.0 / (mx - mn);
  const float mnf = (float)mn, invf = (float)inv;

  const float4* ib = (const float4*)(init + (size_t)r * E);
  float4* hRow = (float4*)(outH + (size_t)r * E);
  float4* bRow = (float4*)(outB + (size_t)r * E);
  const int nf4 = E >> 2;
  for (int i = t; i < nf4; i += 256) {
    float4 v = ib[i];
    float4 h, bb;
    h.x = (0.5f * v.x - mnf) * invf;
    h.y = (0.5f * v.y - mnf) * invf;
    h.z = (0.5f * v.z - mnf) * invf;
    h.w = (0.5f * v.w - mnf) * invf;
    bb.x = (h.x > 0.5f) ? 1.0f : 0.0f;
    bb.y = (h.y > 0.5f) ? 1.0f : 0.0f;
    bb.z = (h.z > 0.5f) ? 1.0f : 0.0f;
    bb.w = (h.w > 0.5f) ? 1.0f : 0.0f;
    hRow[i] = h;
    bRow[i] = bb;
    for (int f = 0; f < factor; ++f) {
      float4* fh = (float4*)(outFH + ((size_t)r * factor + f) * 3584 + foff);
      float4* fb = (float4*)(outFB + ((size_t)r * factor + f) * 3584 + foff);
      fh[i] = h;
      fb[i] = bb;
    }
    if (bb.x + bb.y + bb.z + bb.w > 0.0f) {  // essentially never taken off top-k
      const int c0 = i << 2;
      if (bb.x > 0.0f) { outR[c0 + 0] = 1.0f; outFR[foff + c0 + 0] = 1.0f; }
      if (bb.y > 0.0f) { outR[c0 + 1] = 1.0f; outFR[foff + c0 + 1] = 1.0f; }
      if (bb.z > 0.0f) { outR[c0 + 2] = 1.0f; outFR[foff + c0 + 2] = 1.0f; }
      if (bb.w > 0.0f) { outR[c0 + 3] = 1.0f; outFR[foff + c0 + 3] = 1.0f; }
    }
  }
  __syncthreads();
  if (t < 16) {
    const int gc = tIdx[(size_t)r * 16 + t];
    const double cur = tCur[(size_t)r * 16 + t];
    const double adj = 0.5 * ((double)init[(size_t)r * E + gc] + cur);
    const double H = (adj - mn) * inv;
    const float hf = (float)H;
    const float bf = (H > 0.5) ? 1.0f : 0.0f;
    outH[(size_t)r * E + gc] = hf;
    outB[(size_t)r * E + gc] = bf;
    for (int f = 0; f < factor; ++f) {
      outFH[((size_t)r * factor + f) * 3584 + foff + gc] = hf;
      outFB[((size_t)r * factor + f) * 3584 + foff + gc] = bf;
    }
    if (bf > 0.0f) {
      outR[gc] = 1.0f;       // idempotent 1.0f stores: race-safe
      outFR[foff + gc] = 1.0f;
    }
  }
}

extern "C" void kernel_launch(void* const* d_in, const int* in_sizes, int n_in,
                              void* d_out, int out_size, void* d_ws, size_t ws_size,
                              hipStream_t stream) {
  (void)in_sizes; (void)n_in; (void)out_size; (void)ws_size;
  const float* node0 = (const float*)d_in[0];
  const float* node1 = (const float*)d_in[1];
  const float* node2 = (const float*)d_in[2];
  const float* edge0 = (const float*)d_in[3];
  const float* edge1 = (const float*)d_in[4];
  const float* edge2 = (const float*)d_in[5];
  const float* init0 = (const float*)d_in[6];
  const float* init1 = (const float*)d_in[7];
  const float* init2 = (const float*)d_in[8];
  float* out = (float*)d_out;

  // ws layout: [0..23] u32 min/max per level; [32..55] u64 blend max; topk2 after.
  unsigned char* ws = (unsigned char*)d_ws;
  unsigned int* wsMM = (unsigned int*)ws;
  unsigned long long* wsBlend = (unsigned long long*)(ws + 32);
  int* tIdx2 = (int*)(ws + 64);
  double* tCur2 = (double*)(ws + 64 + 524288);

  // topk0/topk1 scratch inside bins2 output region (consumed before k2 level2 rewrites it)
  float* b2s = out + OFF_B2;
  int* tIdx0 = (int*)b2s;                     // 524288 floats
  double* tCur0 = (double*)(b2s + 524288);    // 1048576 floats
  int* tIdx1 = (int*)(b2s + 1572864);         // 262144 floats
  double* tCur1 = (double*)(b2s + 1835008);   // 524288 floats

  k_init<<<1, 256, 0, stream>>>(out, wsMM, wsBlend);
  k1<<<512, 256, 0, stream>>>(node0, edge0, init0, 2048, tIdx0, tCur0, wsMM + 0, wsBlend + 0);
  k1<<<256, 256, 0, stream>>>(node1, edge1, init1, 1024, tIdx1, tCur1, wsMM + 2, wsBlend + 1);
  k1<<<128, 256, 0, stream>>>(node2, edge2, init2, 512, tIdx2, tCur2, wsMM + 4, wsBlend + 2);
  k2<<<32768, 256, 0, stream>>>(init0, 2048, 1, 0, tIdx0, tCur0, wsMM + 0, wsBlend + 0,
                                out + OFF_H0, out + OFF_B0, out + OFF_FH, out + OFF_FB,
                                out + OFF_R0, out + OFF_RF);
  k2<<<16384, 256, 0, stream>>>(init1, 1024, 2, 2048, tIdx1, tCur1, wsMM + 2, wsBlend + 1,
                                out + OFF_H1, out + OFF_B1, out + OFF_FH, out + OFF_FB,
                                out + OFF_R1, out + OFF_RF);
  k2<<<8192, 256, 0, stream>>>(init2, 512, 4, 3072, tIdx2, tCur2, wsMM + 4, wsBlend + 2,
                                out + OFF_H2, out + OFF_B2, out + OFF_FH, out + OFF_FB,
                                out + OFF_R2, out + OFF_RF);
}

// Round 3
// 2624.723 us; speedup vs baseline: 1.3599x; 1.1287x over previous
//
#include <hip/hip_runtime.h>
#include <cstdint>
#include <cstddef>

#define DIM 64

// ---- output element offsets (float32 elements, reference return order) ----
static constexpr size_t OFF_FH = 0;                  // fused_H   [32768][3584]
static constexpr size_t OFF_H0 = 117440512;          // H0        [32768][2048]
static constexpr size_t OFF_H1 = 184549376;          // H1        [16384][1024]
static constexpr size_t OFF_H2 = 201326592;          // H2        [8192][512]
static constexpr size_t OFF_B0 = 205520896;          // bins0
static constexpr size_t OFF_B1 = 272629760;          // bins1
static constexpr size_t OFF_B2 = 289406976;          // bins2
static constexpr size_t OFF_FB = 293601280;          // fused_bin [32768][3584]
static constexpr size_t OFF_R0 = 411041792;          // retain0 [2048]
static constexpr size_t OFF_R1 = 411043840;          // retain1 [1024]
static constexpr size_t OFF_R2 = 411044864;          // retain2 [512]
static constexpr size_t OFF_RF = 411045376;          // fused_retain [3584]

// f32-grade exp(x) as a double, x >= 0, chain-free (no running max needed).
__device__ __forceinline__ double exp2split(float x) {
  const float f = x * 1.44269504f;
  const int i = (int)f;              // trunc; f >= 0
  const float r = f - (float)i;
  const float e = exp2f(r);          // v_exp_f32, r in [0,1)
  const unsigned long long sc = (unsigned long long)(1023 + i) << 52;
  return (double)e * __longlong_as_double((long long)sc);
}

__device__ __forceinline__ void scan1(float x, int col, unsigned long long* top,
                                      unsigned long long& tmin, double& s) {
  const unsigned long long pk =
      ((unsigned long long)__float_as_uint(x) << 32) |
      (unsigned long long)(0xFFFFFFFFu - (unsigned int)col);
  if (pk > tmin) {  // replace current min of the 16-deep list
#pragma unroll
    for (int q = 0; q < 16; ++q) top[q] = (top[q] == tmin) ? pk : top[q];
    unsigned long long t2 = top[0];
#pragma unroll
    for (int q = 1; q < 16; ++q) t2 = (top[q] < t2) ? top[q] : t2;
    tmin = t2;
  }
  s += exp2split(x);
}

// Zero the retain outputs (sparsely set later) and seed ws atomics.
__global__ void k_init(float* __restrict__ out, unsigned int* __restrict__ wsMM,
                       unsigned long long* __restrict__ wsBlend) {
  const int t = threadIdx.x;
  for (int i = t; i < 7168; i += 256) out[OFF_R0 + i] = 0.0f;
  if (t < 3) {
    wsMM[2 * t + 0] = 0x7F7FFFFFu;  // FLT_MAX bits (init min)
    wsMM[2 * t + 1] = 0u;           // init max (all init values > 0)
    wsBlend[t] = 0ull;              // blend max (positive doubles)
  }
}

// k1 v3: all 3 levels in ONE dispatch (448 blocks -> cross-block phase overlap).
// 128x128 tile, 8x8 per-thread outer product (1 B/MAC LDS traffic), xt aliased
// over nA/nB (67.6 KB -> 2 blocks/CU), A re-staged per tile (L2-hit).
__global__ __launch_bounds__(256) void k1(
    const float* __restrict__ node0, const float* __restrict__ node1, const float* __restrict__ node2,
    const float* __restrict__ edge0, const float* __restrict__ edge1, const float* __restrict__ edge2,
    const float* __restrict__ init0, const float* __restrict__ init1, const float* __restrict__ init2,
    int* __restrict__ tIdx0, int* __restrict__ tIdx1, int* __restrict__ tIdx2,
    double* __restrict__ tCur0, double* __restrict__ tCur1, double* __restrict__ tCur2,
    unsigned int* __restrict__ wsMM, unsigned long long* __restrict__ wsBlend) {
  __shared__ float smem[128 * 132];  // nA [64][132] | nB [64][132]; xt [128][132] aliases both
  __shared__ float sMin[4], sMax[4];
  __shared__ double sBlendW[4];

  const int b = blockIdx.x;
  int lvl, bloc, E;
  const float *node, *edge, *init;
  int* tIdx;
  double* tCur;
  if (b < 256)      { lvl = 0; bloc = b;       node = node0; edge = edge0; init = init0; tIdx = tIdx0; tCur = tCur0; E = 2048; }
  else if (b < 384) { lvl = 1; bloc = b - 256; node = node1; edge = edge1; init = init1; tIdx = tIdx1; tCur = tCur1; E = 1024; }
  else              { lvl = 2; bloc = b - 384; node = node2; edge = edge2; init = init2; tIdx = tIdx2; tCur = tCur2; E = 512;  }

  const int t = threadIdx.x;
  const int lane = t & 63;
  const int wave = t >> 6;
  const int row0 = bloc * 128;
  const int tr8 = (t & 15) << 3;   // GEMM row base (8 rows)
  const int tc8 = (t >> 4) << 3;   // GEMM col base (8 cols)
  const int srow = t >> 1;         // scan row (0..127)
  const int sl = t & 1;            // scan half (64 cols each)
  float* nB = smem + 64 * 132;

  unsigned long long top[16];
#pragma unroll
  for (int q = 0; q < 16; ++q) top[q] = (unsigned long long)q;  // sentinels < any real pack
  unsigned long long tmin = 0ull;
  double s0 = 0.0, s1 = 0.0;

  for (int c0 = 0; c0 < E; c0 += 128) {
    __syncthreads();  // prev tile's scan done; smem free
    // ---- stage A (k-major) + B (k-major), transposed writes ----
#pragma unroll
    for (int p = 0; p < 8; ++p) {
      const int idx = t + 256 * p;
      const int r = idx >> 4;            // 0..127
      const int kc = (idx & 15) << 2;    // 0,4,..,60
      const float4 v = *(const float4*)(node + (size_t)(row0 + r) * DIM + kc);
      smem[(kc + 0) * 132 + r] = v.x;
      smem[(kc + 1) * 132 + r] = v.y;
      smem[(kc + 2) * 132 + r] = v.z;
      smem[(kc + 3) * 132 + r] = v.w;
      const float4 w = *(const float4*)(edge + (size_t)(c0 + r) * DIM + kc);
      nB[(kc + 0) * 132 + r] = w.x;
      nB[(kc + 1) * 132 + r] = w.y;
      nB[(kc + 2) * 132 + r] = w.z;
      nB[(kc + 3) * 132 + r] = w.w;
    }
    __syncthreads();

    // ---- 128x128 GEMM, 8x8 per thread ----
    float acc[8][8];
#pragma unroll
    for (int i = 0; i < 8; ++i)
#pragma unroll
      for (int j = 0; j < 8; ++j) acc[i][j] = 0.0f;

#pragma unroll 4
    for (int k = 0; k < 64; ++k) {
      const float4 a0 = *(const float4*)&smem[k * 132 + tr8];
      const float4 a1 = *(const float4*)&smem[k * 132 + tr8 + 4];
      const float4 b0 = *(const float4*)&nB[k * 132 + tc8];
      const float4 b1 = *(const float4*)&nB[k * 132 + tc8 + 4];
      const float av[8] = {a0.x, a0.y, a0.z, a0.w, a1.x, a1.y, a1.z, a1.w};
      const float bv[8] = {b0.x, b0.y, b0.z, b0.w, b1.x, b1.y, b1.z, b1.w};
#pragma unroll
      for (int i = 0; i < 8; ++i)
#pragma unroll
        for (int j = 0; j < 8; ++j) acc[i][j] = fmaf(av[i], bv[j], acc[i][j]);
    }
    __syncthreads();  // all reads of nA/nB done before xt overwrites them

    // ---- epilogue: xt = relu(3*acc), aliased over nA/nB ----
#pragma unroll
    for (int i = 0; i < 8; ++i) {
      float4 h0, h1;
      h0.x = fmaxf(3.0f * acc[i][0], 0.0f); h0.y = fmaxf(3.0f * acc[i][1], 0.0f);
      h0.z = fmaxf(3.0f * acc[i][2], 0.0f); h0.w = fmaxf(3.0f * acc[i][3], 0.0f);
      h1.x = fmaxf(3.0f * acc[i][4], 0.0f); h1.y = fmaxf(3.0f * acc[i][5], 0.0f);
      h1.z = fmaxf(3.0f * acc[i][6], 0.0f); h1.w = fmaxf(3.0f * acc[i][7], 0.0f);
      *(float4*)&smem[(tr8 + i) * 132 + tc8] = h0;
      *(float4*)&smem[(tr8 + i) * 132 + tc8 + 4] = h1;
    }
    __syncthreads();

    // ---- scan: 2 threads per row, 64 cols each ----
#pragma unroll 4
    for (int j = 0; j < 16; ++j) {
      const int cl = (sl << 6) + (j << 2);
      const float4 v = *(const float4*)&smem[srow * 132 + cl];
      const int cb = c0 + cl;
      scan1(v.x, cb + 0, top, tmin, s0);
      scan1(v.y, cb + 1, top, tmin, s1);
      scan1(v.z, cb + 2, top, tmin, s0);
      scan1(v.w, cb + 3, top, tmin, s1);
    }
  }

  // ---- merge 2x top-16 -> row top-16 ----
  unsigned long long win[8];
#pragma unroll 1
  for (int round = 0; round < 16; ++round) {
    unsigned long long lm = top[0];
#pragma unroll
    for (int q = 1; q < 16; ++q) lm = (top[q] > lm) ? top[q] : lm;
    { const unsigned long long o = __shfl_xor(lm, 1); lm = (o > lm) ? o : lm; }
#pragma unroll
    for (int q = 0; q < 16; ++q) top[q] = (top[q] == lm) ? 0ull : top[q];
    if ((round & 1) == sl) win[round >> 1] = lm;
  }

  double sAll = s0 + s1;
  sAll += __shfl_xor(sAll, 1);

  // ---- f64 head recompute (8 winners per thread) ----
  const int grow = row0 + srow;
  const float4* n4 = (const float4*)(node + (size_t)grow * DIM);
  double eh[8];
  int gcv[8];
  double h32sum = 0.0, ehsum = 0.0;
#pragma unroll 1
  for (int w = 0; w < 8; ++w) {
    const float x32 = __uint_as_float((unsigned int)(win[w] >> 32));
    const unsigned int gc = 0xFFFFFFFFu - (unsigned int)(win[w] & 0xFFFFFFFFull);
    const float4* e4 = (const float4*)(edge + (size_t)gc * DIM);
    double acc = 0.0;
#pragma unroll
    for (int j = 0; j < 16; ++j) {
      const float4 a = n4[j], bb = e4[j];
      acc += (double)a.x * (double)bb.x + (double)a.y * (double)bb.y +
             (double)a.z * (double)bb.z + (double)a.w * (double)bb.w;
    }
    const double x64 = fmax(3.0 * acc, 0.0);
    eh[w] = exp(x64);
    ehsum += eh[w];
    h32sum += exp2split(x32);
    gcv[w] = (int)gc;
  }
  h32sum += __shfl_xor(h32sum, 1);
  ehsum += __shfl_xor(ehsum, 1);
  const double sFix = fmax(sAll - h32sum, 0.0) + ehsum;  // swap f32-grade head for f64 head

  double blend = 0.0;
#pragma unroll 1
  for (int w = 0; w < 8; ++w) {
    const double cur = eh[w] / sFix;
    tIdx[(size_t)grow * 16 + 2 * w + sl] = gcv[w];
    tCur[(size_t)grow * 16 + 2 * w + sl] = cur;
    blend = fmax(blend, 0.5 * ((double)init[(size_t)grow * E + gcv[w]] + cur));
  }
#pragma unroll
  for (int d = 1; d < 64; d <<= 1) {
    const double o = __shfl_xor(blend, d);
    blend = fmax(blend, o);
  }
  if (lane == 0) sBlendW[wave] = blend;

  // ---- streaming min/max of adj_init for this block's 128 rows ----
  float imn = __uint_as_float(0x7F7FFFFFu), imx = 0.0f;
  const float4* ib = (const float4*)(init + (size_t)row0 * E);
  const int tot = (128 * E) >> 2;
  for (int i = t; i < tot; i += 256) {
    const float4 v = ib[i];
    imn = fminf(imn, fminf(fminf(v.x, v.y), fminf(v.z, v.w)));
    imx = fmaxf(imx, fmaxf(fmaxf(v.x, v.y), fmaxf(v.z, v.w)));
  }
#pragma unroll
  for (int d = 1; d < 64; d <<= 1) {
    imn = fminf(imn, __shfl_xor(imn, d));
    imx = fmaxf(imx, __shfl_xor(imx, d));
  }
  if (lane == 0) { sMin[wave] = imn; sMax[wave] = imx; }
  __syncthreads();
  if (t == 0) {
    const float a = fminf(fminf(sMin[0], sMin[1]), fminf(sMin[2], sMin[3]));
    const float bmx = fmaxf(fmaxf(sMax[0], sMax[1]), fmaxf(sMax[2], sMax[3]));
    atomicMin(wsMM + 2 * lvl + 0, __float_as_uint(a));
    atomicMax(wsMM + 2 * lvl + 1, __float_as_uint(bmx));
    double bl = sBlendW[0];
#pragma unroll
    for (int i = 1; i < 4; ++i) bl = fmax(bl, sBlendW[i]);
    atomicMax(wsBlend + lvl, (unsigned long long)__double_as_longlong(bl));
  }
}

// k2 fused: one block per fused row r; build the full 3584-col H/bin row in LDS
// (base pass + 48 top-k f64 fixes), then stream every output exactly once.
__global__ __launch_bounds__(256) void k2(
    const float* __restrict__ init0, const float* __restrict__ init1, const float* __restrict__ init2,
    const int* __restrict__ tIdx0, const int* __restrict__ tIdx1, const int* __restrict__ tIdx2,
    const double* __restrict__ tCur0, const double* __restrict__ tCur1, const double* __restrict__ tCur2,
    const unsigned int* __restrict__ wsMM, const unsigned long long* __restrict__ wsBlend,
    float* __restrict__ out) {
  __shared__ float fH[3584];
  __shared__ float fB[3584];
  const int r = blockIdx.x;
  const int t = threadIdx.x;
  const int r1 = r >> 1, r2 = r >> 2;

  const double mn0 = 0.5 * (double)__uint_as_float(wsMM[0]);
  const double mx0 = fmax(0.5 * (double)__uint_as_float(wsMM[1]),
                          __longlong_as_double((long long)wsBlend[0]));
  const double inv0 = 1.0 / (mx0 - mn0);
  const double mn1 = 0.5 * (double)__uint_as_float(wsMM[2]);
  const double mx1 = fmax(0.5 * (double)__uint_as_float(wsMM[3]),
                          __longlong_as_double((long long)wsBlend[1]));
  const double inv1 = 1.0 / (mx1 - mn1);
  const double mn2 = 0.5 * (double)__uint_as_float(wsMM[4]);
  const double mx2 = fmax(0.5 * (double)__uint_as_float(wsMM[5]),
                          __longlong_as_double((long long)wsBlend[2]));
  const double inv2 = 1.0 / (mx2 - mn2);

  // ---- phase 1: base values into LDS ----
  for (int i = t; i < 896; i += 256) {
    const int c = i << 2;
    float4 v;
    float mnl, il;
    size_t offR, offF;
    if (c < 2048)      { v = *(const float4*)(init0 + (size_t)r  * 2048 + c);
                         mnl = (float)mn0; il = (float)inv0; offR = OFF_R0; offF = (size_t)c; }
    else if (c < 3072) { v = *(const float4*)(init1 + (size_t)r1 * 1024 + (c - 2048));
                         mnl = (float)mn1; il = (float)inv1; offR = OFF_R1 - 2048; offF = (size_t)c; }
    else               { v = *(const float4*)(init2 + (size_t)r2 * 512 + (c - 3072));
                         mnl = (float)mn2; il = (float)inv2; offR = OFF_R2 - 3072; offF = (size_t)c; }
    float4 h, bb;
    h.x = (0.5f * v.x - mnl) * il;
    h.y = (0.5f * v.y - mnl) * il;
    h.z = (0.5f * v.z - mnl) * il;
    h.w = (0.5f * v.w - mnl) * il;
    bb.x = (h.x > 0.5f) ? 1.0f : 0.0f;
    bb.y = (h.y > 0.5f) ? 1.0f : 0.0f;
    bb.z = (h.z > 0.5f) ? 1.0f : 0.0f;
    bb.w = (h.w > 0.5f) ? 1.0f : 0.0f;
    *(float4*)&fH[c] = h;
    *(float4*)&fB[c] = bb;
    if (bb.x + bb.y + bb.z + bb.w > 0.0f) {  // safety: essentially never taken off top-k
      if (bb.x > 0.0f) { out[offR + c + 0] = 1.0f; out[OFF_RF + c + 0] = 1.0f; }
      if (bb.y > 0.0f) { out[offR + c + 1] = 1.0f; out[OFF_RF + c + 1] = 1.0f; }
      if (bb.z > 0.0f) { out[offR + c + 2] = 1.0f; out[OFF_RF + c + 2] = 1.0f; }
      if (bb.w > 0.0f) { out[offR + c + 3] = 1.0f; out[OFF_RF + c + 3] = 1.0f; }
    }
  }
  __syncthreads();

  // ---- phase 2: 48 top-k f64 fixes + retains ----
  if (t < 48) {
    const int lv = t >> 4, j = t & 15;
    int rowl, El, off;
    const int* ti; const double* tc; const float* in;
    size_t offR;
    double mnl, il;
    if (lv == 0)      { rowl = r;  El = 2048; off = 0;    ti = tIdx0; tc = tCur0; in = init0; offR = OFF_R0; mnl = mn0; il = inv0; }
    else if (lv == 1) { rowl = r1; El = 1024; off = 2048; ti = tIdx1; tc = tCur1; in = init1; offR = OFF_R1; mnl = mn1; il = inv1; }
    else              { rowl = r2; El = 512;  off = 3072; ti = tIdx2; tc = tCur2; in = init2; offR = OFF_R2; mnl = mn2; il = inv2; }
    const int gc = ti[(size_t)rowl * 16 + j];
    const double cur = tc[(size_t)rowl * 16 + j];
    const double adj = 0.5 * ((double)in[(size_t)rowl * El + gc] + cur);
    const double H = (adj - mnl) * il;
    const float hf = (float)H;
    const float bf = (H > 0.5) ? 1.0f : 0.0f;
    fH[off + gc] = hf;
    fB[off + gc] = bf;
    if (bf > 0.0f) {
      out[offR + gc] = 1.0f;            // idempotent: race-safe across blocks
      out[OFF_RF + off + gc] = 1.0f;
    }
  }
  __syncthreads();

  // ---- phase 3: stream LDS -> global, each location written exactly once ----
  const float4* sH = (const float4*)fH;
  const float4* sB = (const float4*)fB;
  float4* FH = (float4*)(out + OFF_FH + (size_t)r * 3584);
  float4* FB = (float4*)(out + OFF_FB + (size_t)r * 3584);
  float4* H0 = (float4*)(out + OFF_H0 + (size_t)r * 2048);
  float4* B0 = (float4*)(out + OFF_B0 + (size_t)r * 2048);
  for (int i = t; i < 896; i += 256) { FH[i] = sH[i]; FB[i] = sB[i]; }
  for (int i = t; i < 512; i += 256) { H0[i] = sH[i]; B0[i] = sB[i]; }
  if ((r & 1) == 0) {
    float4* H1 = (float4*)(out + OFF_H1 + (size_t)r1 * 1024);
    float4* B1 = (float4*)(out + OFF_B1 + (size_t)r1 * 1024);
    H1[t] = sH[512 + t];
    B1[t] = sB[512 + t];
  }
  if ((r & 3) == 0 && t < 128) {
    float4* H2 = (float4*)(out + OFF_H2 + (size_t)r2 * 512);
    float4* B2 = (float4*)(out + OFF_B2 + (size_t)r2 * 512);
    H2[t] = sH[768 + t];
    B2[t] = sB[768 + t];
  }
}

extern "C" void kernel_launch(void* const* d_in, const int* in_sizes, int n_in,
                              void* d_out, int out_size, void* d_ws, size_t ws_size,
                              hipStream_t stream) {
  (void)in_sizes; (void)n_in; (void)out_size; (void)ws_size;
  const float* node0 = (const float*)d_in[0];
  const float* node1 = (const float*)d_in[1];
  const float* node2 = (const float*)d_in[2];
  const float* edge0 = (const float*)d_in[3];
  const float* edge1 = (const float*)d_in[4];
  const float* edge2 = (const float*)d_in[5];
  const float* init0 = (const float*)d_in[6];
  const float* init1 = (const float*)d_in[7];
  const float* init2 = (const float*)d_in[8];
  float* out = (float*)d_out;

  // ws layout (~11.1 MB used of multi-GB ws): atomics, then topk idx/cur.
  unsigned char* ws = (unsigned char*)d_ws;
  unsigned int* wsMM = (unsigned int*)ws;                       // 6 u32
  unsigned long long* wsBlend = (unsigned long long*)(ws + 32); // 3 u64
  int*    tIdx0 = (int*)(ws + 64);
  int*    tIdx1 = (int*)(ws + 64 + (size_t)(2 << 20));
  int*    tIdx2 = (int*)(ws + 64 + (size_t)(3 << 20));
  double* tCur0 = (double*)(ws + 64 + (size_t)(4 << 20));
  double* tCur1 = (double*)(ws + 64 + (size_t)(8 << 20));
  double* tCur2 = (double*)(ws + 64 + (size_t)(10 << 20));

  k_init<<<1, 256, 0, stream>>>(out, wsMM, wsBlend);
  k1<<<448, 256, 0, stream>>>(node0, node1, node2, edge0, edge1, edge2,
                              init0, init1, init2, tIdx0, tIdx1, tIdx2,
                              tCur0, tCur1, tCur2, wsMM, wsBlend);
  k2<<<32768, 256, 0, stream>>>(init0, init1, init2, tIdx0, tIdx1, tIdx2,
                                tCur0, tCur1, tCur2, wsMM, wsBlend, out);
}